// Round 1
// baseline (10496.123 us; speedup 1.0000x reference)
//
#include <hip/hip_runtime.h>

// LSTM 2-layer, T=512, B=64, I=H=1024, fp32 in/out, bf16 MFMA compute.
// Phase 1: convert weights to bf16 Wcat=[Wx|Wh] ([4096 x 2048], B^T layout), x -> bf16.
// Phase 2: 513 pipelined step launches; launch s runs layer0(step s) on blocks 0-63
//          and layer1(step s-1) on blocks 64-127 (both consume h0_{s-1}).
// Phase 3: epilogue assembles h (2,B,H) and c (2,B,H) outputs after out (T,B,H).

#define T_STEPS 512
#define BATCH   64
#define HDIM    1024
#define KTOT    2048
#define BK      128
#define NITER   (KTOT / BK)   // 16
#define LDSTR   136           // 128 + 8 pad (16B-aligned stride, 2-way bank alias = free)
#define BH      (BATCH * HDIM)  // 65536

typedef __bf16 bf16x8 __attribute__((ext_vector_type(8)));
typedef __bf16 bf16x4 __attribute__((ext_vector_type(4)));
typedef float  f32x4  __attribute__((ext_vector_type(4)));

__device__ __forceinline__ float sigm_(float x) { return 1.0f / (1.0f + __expf(-x)); }
__device__ __forceinline__ float tanh_(float x) {
    float e = __expf(-2.0f * fabsf(x));     // e in (0,1], no overflow
    float t = (1.0f - e) / (1.0f + e);
    return copysignf(t, x);
}

// One LSTM cell GEMM+elementwise for 16 h-columns per block.
// Gate order along 4H rows of Wcat: i, j, f, o (chunks of 1024).
__global__ __launch_bounds__(256) void lstm_step2(
    const __bf16* __restrict__ Ax0, const __bf16* __restrict__ Ah0,
    const __bf16* __restrict__ W0,  float* __restrict__ c0,
    __bf16* __restrict__ hb0, float* __restrict__ hf0, int en0,
    const __bf16* __restrict__ Ax1, const __bf16* __restrict__ Ah1,
    const __bf16* __restrict__ W1,  float* __restrict__ c1,
    __bf16* __restrict__ hb1, float* __restrict__ hf1, int en1)
{
    __shared__ __bf16 As[64 * LDSTR];
    __shared__ __bf16 Bs[64 * LDSTR];

    int bid = blockIdx.x;
    const __bf16 *Ax, *Ah, *W;
    float *c, *hf;
    __bf16 *hb;
    if (bid < 64) {
        if (!en0) return;
        Ax = Ax0; Ah = Ah0; W = W0; c = c0; hb = hb0; hf = hf0;
    } else {
        if (!en1) return;
        Ax = Ax1; Ah = Ah1; W = W1; c = c1; hb = hb1; hf = hf1; bid -= 64;
    }
    const int n0   = bid * 16;           // h-column base for this block
    const int tid  = threadIdx.x;
    const int wave = tid >> 6;
    const int lane = tid & 63;
    const int sr   = tid >> 2;           // staging row 0..63
    const int kc   = (tid & 3) * 32;     // staging k-chunk within BK
    // B staging: row sr -> gate group g=sr>>4, col c=sr&15 -> W row g*1024 + n0 + c
    const int wrow = (sr >> 4) * 1024 + n0 + (sr & 15);

    f32x4 acc[4] = {};                   // i, j, f, o accumulators (16x16 tile each)

    bf16x8 pa[4], pb[4];
    {   // prefetch kb = 0 (x-part)
        const __bf16* s = Ax + sr * 1024 + kc;
        #pragma unroll
        for (int u = 0; u < 4; ++u) pa[u] = *(const bf16x8*)(s + u * 8);
        const __bf16* w = W + wrow * 2048 + kc;
        #pragma unroll
        for (int u = 0; u < 4; ++u) pb[u] = *(const bf16x8*)(w + u * 8);
    }

    for (int it = 0; it < NITER; ++it) {
        #pragma unroll
        for (int u = 0; u < 4; ++u) *(bf16x8*)&As[sr * LDSTR + kc + u * 8] = pa[u];
        #pragma unroll
        for (int u = 0; u < 4; ++u) *(bf16x8*)&Bs[sr * LDSTR + kc + u * 8] = pb[u];
        __syncthreads();

        if (it + 1 < NITER) {            // prefetch next K-block during compute
            int kb = (it + 1) * BK;      // 1024 boundary never crossed inside a BK
            const __bf16* s = (kb < 1024 ? Ax + sr * 1024 + kb
                                         : Ah + sr * 1024 + (kb - 1024)) + kc;
            #pragma unroll
            for (int u = 0; u < 4; ++u) pa[u] = *(const bf16x8*)(s + u * 8);
            const __bf16* w = W + wrow * 2048 + kb + kc;
            #pragma unroll
            for (int u = 0; u < 4; ++u) pb[u] = *(const bf16x8*)(w + u * 8);
        }

        const int lrow = lane & 15;
        const int lk   = (lane >> 4) * 8;
        #pragma unroll
        for (int s4 = 0; s4 < 4; ++s4) { // 4 sub-K of 32
            bf16x8 af = *(bf16x8*)&As[(wave * 16 + lrow) * LDSTR + s4 * 32 + lk];
            #pragma unroll
            for (int g = 0; g < 4; ++g) {
                bf16x8 bf = *(bf16x8*)&Bs[(g * 16 + lrow) * LDSTR + s4 * 32 + lk];
                acc[g] = __builtin_amdgcn_mfma_f32_16x16x32_bf16(af, bf, acc[g], 0, 0, 0);
            }
        }
        __syncthreads();
    }

    // Elementwise cell update. D layout: col = lane&15, row = (lane>>4)*4 + r.
    const int n  = n0 + (lane & 15);
    const int mb = wave * 16 + (lane >> 4) * 4;
    #pragma unroll
    for (int r = 0; r < 4; ++r) {
        int m = mb + r;
        float gi = acc[0][r], gj = acc[1][r], gf = acc[2][r], go = acc[3][r];
        float cold = c[m * HDIM + n];
        float cn = cold * sigm_(gf + 1.0f) + sigm_(gi) * tanh_(gj);
        float hn = sigm_(go) * tanh_(cn);
        c[m * HDIM + n]  = cn;
        hb[m * HDIM + n] = (__bf16)hn;
        hf[m * HDIM + n] = hn;
    }
}

// Wcat[n][k] = k<1024 ? Wx[n][k] : Wh[n][k-1024], fp32 -> bf16. 4 elems/thread.
__global__ void convW(const float* __restrict__ Wx, const float* __restrict__ Wh,
                      __bf16* __restrict__ dst) {
    int i = blockIdx.x * 256 + threadIdx.x;   // 0 .. 2097151
    int e = i * 4;
    int n = e >> 11;
    int k = e & 2047;
    const float* src = (k < 1024) ? (Wx + n * 1024 + k) : (Wh + n * 1024 + (k - 1024));
    float4 v = *(const float4*)src;
    bf16x4 o = { (__bf16)v.x, (__bf16)v.y, (__bf16)v.z, (__bf16)v.w };
    *(bf16x4*)(dst + e) = o;
}

__global__ void convX(const float* __restrict__ x, __bf16* __restrict__ dst) {
    int i = blockIdx.x * 256 + threadIdx.x;   // 0 .. 8388607
    int e = i * 4;
    float4 v = *(const float4*)(x + e);
    bf16x4 o = { (__bf16)v.x, (__bf16)v.y, (__bf16)v.z, (__bf16)v.w };
    *(bf16x4*)(dst + e) = o;
}

__global__ void initz(__bf16* h0s, __bf16* h1s, float* c0, float* c1) {
    int i = blockIdx.x * 256 + threadIdx.x;   // 0 .. 65535
    h0s[i] = (__bf16)0.0f;
    h1s[i] = (__bf16)0.0f;
    c0[i] = 0.0f;
    c1[i] = 0.0f;
}

__global__ void epilogue_k(float* __restrict__ out, const float* __restrict__ h0f,
                           const float* __restrict__ c0, const float* __restrict__ c1) {
    int i = blockIdx.x * 256 + threadIdx.x;   // 0 .. 65535
    float* hout = out + (size_t)T_STEPS * BH;
    hout[i]      = h0f[i];                               // h[0] = final h0
    hout[BH + i] = out[(size_t)(T_STEPS - 1) * BH + i];  // h[1] = out[T-1]
    float* cout = hout + 2 * BH;
    cout[i]      = c0[i];
    cout[BH + i] = c1[i];
}

extern "C" void kernel_launch(void* const* d_in, const int* in_sizes, int n_in,
                              void* d_out, int out_size, void* d_ws, size_t ws_size,
                              hipStream_t stream) {
    const float* x   = (const float*)d_in[0];
    const float* Wx0 = (const float*)d_in[1];
    const float* Wh0 = (const float*)d_in[2];
    const float* Wx1 = (const float*)d_in[3];
    const float* Wh1 = (const float*)d_in[4];
    float* out = (float*)d_out;

    // Workspace carve-up (~97.3 MB total)
    char* p = (char*)d_ws;
    __bf16* W0c = (__bf16*)p; p += (size_t)4096 * 2048 * 2;   // 16 MB
    __bf16* W1c = (__bf16*)p; p += (size_t)4096 * 2048 * 2;   // 16 MB
    __bf16* Xb  = (__bf16*)p; p += (size_t)T_STEPS * BH * 2;  // 64 MB
    __bf16* h0s = (__bf16*)p; p += (size_t)2 * BH * 2;        // ping-pong
    __bf16* h1s = (__bf16*)p; p += (size_t)2 * BH * 2;
    float*  c0v = (float*)p;  p += (size_t)BH * 4;
    float*  c1v = (float*)p;  p += (size_t)BH * 4;
    float*  h0f = (float*)p;  p += (size_t)BH * 4;

    convW<<<8192, 256, 0, stream>>>(Wx0, Wh0, W0c);
    convW<<<8192, 256, 0, stream>>>(Wx1, Wh1, W1c);
    convX<<<32768, 256, 0, stream>>>(x, Xb);
    initz<<<256, 256, 0, stream>>>(h0s, h1s, c0v, c1v);

    for (int s = 0; s <= T_STEPS; ++s) {
        int en0 = (s < T_STEPS);
        int en1 = (s >= 1);
        int t1  = en1 ? (s - 1) : 0;
        // Both layer0(s) and layer1(s-1) read h0_{s-1}, which lives in slot s&1.
        const __bf16* Ax0 = Xb + (size_t)(en0 ? s : 0) * BH;
        const __bf16* Ah0 = h0s + (size_t)(s & 1) * BH;
        __bf16*       hb0 = h0s + (size_t)((s & 1) ^ 1) * BH;
        const __bf16* Ax1 = h0s + (size_t)(s & 1) * BH;
        const __bf16* Ah1 = h1s + (size_t)(t1 & 1) * BH;
        __bf16*       hb1 = h1s + (size_t)((t1 & 1) ^ 1) * BH;
        float*        o1  = out + (size_t)t1 * BH;
        lstm_step2<<<128, 256, 0, stream>>>(Ax0, Ah0, W0c, c0v, hb0, h0f, en0,
                                            Ax1, Ah1, W1c, c1v, hb1, o1, en1);
    }

    epilogue_k<<<256, 256, 0, stream>>>(out, h0f, c0v, c1v);
}